// Round 8
// baseline (257.469 us; speedup 1.0000x reference)
//
#include <hip/hip_runtime.h>
#include <hip/hip_bf16.h>
#include <cstdint>
#include <cmath>

#define N_TOK 8192
#define CDIM  768
#define HDIM  3072
#define NEXP  8
#define NBLK  256     // router/gather blocks, 32 tokens each

typedef __bf16 bf16;
typedef __bf16 bf16x4 __attribute__((ext_vector_type(4)));
typedef __bf16 bf16x8 __attribute__((ext_vector_type(8)));
typedef float  f32x4  __attribute__((ext_vector_type(4)));

// ws byte offsets
#define WS_BE      0u          // 8192 int
#define WS_TPROB   32768u      // 8192 f32
#define WS_CNTB    65536u      // 256*8 int
#define WS_IMPB    73728u      // 256*8 f32
#define WS_BASEB   81920u      // 256*8 int
#define WS_CNT     90112u      // 8 int
#define WS_OFF     90176u      // 9 int
#define WS_TOKMAP  98304u      // 9216 int
#define WS_TPG     137216u     // 9216 f32  -> ends 174080
#define WS_XGT     (1u<<20)    // 72*12*16384 = 14,155,776
#define WS_W1T     (16u<<20)   // 37,748,736 -> ends 54,525,952
#define WS_HBUF    (56u<<20)   // 72*48*16384 = 56,623,104 -> ends 115,343,360
#define WS_W2T     (1u<<20)    // aliases XGT/W1T, written after ffn1

__device__ __forceinline__ void load16_lds(const void* g, void* l) {
  __builtin_amdgcn_global_load_lds(
      (const __attribute__((address_space(1))) void*)g,
      (__attribute__((address_space(3))) void*)l, 16, 0, 0);
}

// ---------------------------------------------------------------------------
// Router: 256 blocks x 32 tokens, wave-per-token (8 tokens/wave).
// Router weights live in 96 VGPRs per lane. Zero global atomics.
// ---------------------------------------------------------------------------
__global__ __launch_bounds__(256) void router3(
    const float* __restrict__ x, const float* __restrict__ Wr,
    float* __restrict__ tprob, int* __restrict__ be_out,
    int* __restrict__ cnt_blk, float* __restrict__ imp_blk)
{
  const int tid = threadIdx.x, lane = tid & 63, wv = tid >> 6;
  const int b = blockIdx.x;
  __shared__ int cnt_l[NEXP];
  __shared__ float imp_l[4][NEXP];
  if (tid < NEXP) cnt_l[tid] = 0;

  // wreg[j*4+q][e] = Wr[c][e], c = j*256 + lane*4 + q
  float wreg[12][8];
  #pragma unroll
  for (int j = 0; j < 3; ++j)
    #pragma unroll
    for (int q = 0; q < 4; ++q) {
      const float4* p = (const float4*)(Wr + (size_t)(j * 256 + lane * 4 + q) * 8);
      float4 lo = p[0], hi = p[1];
      wreg[j*4+q][0] = lo.x; wreg[j*4+q][1] = lo.y;
      wreg[j*4+q][2] = lo.z; wreg[j*4+q][3] = lo.w;
      wreg[j*4+q][4] = hi.x; wreg[j*4+q][5] = hi.y;
      wreg[j*4+q][6] = hi.z; wreg[j*4+q][7] = hi.w;
    }

  float impacc[NEXP];
  #pragma unroll
  for (int e = 0; e < NEXP; ++e) impacc[e] = 0.0f;
  __syncthreads();

  #pragma unroll 1
  for (int t = 0; t < 8; ++t) {
    const int tok = b * 32 + wv * 8 + t;
    float4 xv[3];
    #pragma unroll
    for (int j = 0; j < 3; ++j)
      xv[j] = *(const float4*)(x + (size_t)tok * CDIM + j * 256 + lane * 4);

    float acc[NEXP];
    #pragma unroll
    for (int e = 0; e < NEXP; ++e) acc[e] = 0.0f;
    #pragma unroll
    for (int j = 0; j < 3; ++j) {
      const float xa[4] = {xv[j].x, xv[j].y, xv[j].z, xv[j].w};
      #pragma unroll
      for (int q = 0; q < 4; ++q)
        #pragma unroll
        for (int e = 0; e < NEXP; ++e)
          acc[e] = fmaf(xa[q], wreg[j*4+q][e], acc[e]);
    }
    #pragma unroll
    for (int e = 0; e < NEXP; ++e) {
      float v = acc[e];
      v += __shfl_xor(v, 1);  v += __shfl_xor(v, 2);  v += __shfl_xor(v, 4);
      v += __shfl_xor(v, 8);  v += __shfl_xor(v, 16); v += __shfl_xor(v, 32);
      acc[e] = v;
    }
    float m = acc[0]; int be = 0;
    #pragma unroll
    for (int e = 1; e < NEXP; ++e) if (acc[e] > m) { m = acc[e]; be = e; }
    float pr[NEXP]; float s = 0.0f;
    #pragma unroll
    for (int e = 0; e < NEXP; ++e) { pr[e] = __expf(acc[e] - m); s += pr[e]; }
    const float inv = 1.0f / s;
    #pragma unroll
    for (int e = 0; e < NEXP; ++e) impacc[e] += pr[e] * inv;
    if (lane == 0) {
      tprob[tok]  = pr[be] * inv;
      be_out[tok] = be;
      atomicAdd(&cnt_l[be], 1);          // LDS atomic
    }
  }

  if (lane == 0) {
    #pragma unroll
    for (int e = 0; e < NEXP; ++e) imp_l[wv][e] = impacc[e];
  }
  __syncthreads();
  if (tid < NEXP) {
    cnt_blk[b * NEXP + tid] = cnt_l[tid];
    imp_blk[b * NEXP + tid] =
        imp_l[0][tid] + imp_l[1][tid] + imp_l[2][tid] + imp_l[3][tid];
  }
}

// ---------------------------------------------------------------------------
// Scan: one block, 256 threads. Per-expert exclusive scan over 256 blocks,
// padded offsets, counts, importance, aux loss. No atomics anywhere.
// ---------------------------------------------------------------------------
__global__ __launch_bounds__(256) void scan_kernel(
    const int* __restrict__ cnt_blk, const float* __restrict__ imp_blk,
    int* __restrict__ counts, int* __restrict__ off,
    int* __restrict__ base_blk, float* __restrict__ out_aux)
{
  const int tid = threadIdx.x, lane = tid & 63, wv = tid >> 6;
  __shared__ int   wsum[NEXP][4];
  __shared__ float wimp[NEXP][4];
  __shared__ int   off_s[9];

  int pref[NEXP];
  #pragma unroll
  for (int e = 0; e < NEXP; ++e) {
    int v = cnt_blk[tid * NEXP + e];
    int inc = v;
    #pragma unroll
    for (int o = 1; o < 64; o <<= 1) {
      int n = __shfl_up(inc, o);
      if (lane >= o) inc += n;
    }
    if (lane == 63) wsum[e][wv] = inc;
    pref[e] = inc - v;

    float f = imp_blk[tid * NEXP + e];
    f += __shfl_xor(f, 1);  f += __shfl_xor(f, 2);  f += __shfl_xor(f, 4);
    f += __shfl_xor(f, 8);  f += __shfl_xor(f, 16); f += __shfl_xor(f, 32);
    if (lane == 0) wimp[e][wv] = f;
  }
  __syncthreads();
  if (tid == 0) {
    int o = 0; float aux = 0.0f;
    #pragma unroll
    for (int e = 0; e < NEXP; ++e) {
      int tot = wsum[e][0] + wsum[e][1] + wsum[e][2] + wsum[e][3];
      float im = wimp[e][0] + wimp[e][1] + wimp[e][2] + wimp[e][3];
      counts[e] = tot;
      aux += im * (float)tot;
      off_s[e] = o;
      o += (tot + 127) & ~127;
    }
    off_s[8] = o;
    out_aux[0] = (float)NEXP * aux / ((float)N_TOK * (float)N_TOK);
    for (int i = 0; i < 9; ++i) off[i] = off_s[i];
  }
  __syncthreads();
  #pragma unroll
  for (int e = 0; e < NEXP; ++e) {
    int wofs = 0;
    #pragma unroll
    for (int w = 0; w < 4; ++w) if (w < wv) wofs += wsum[e][w];
    base_blk[tid * NEXP + e] = off_s[e] + wofs + pref[e];
  }
}

// ---------------------------------------------------------------------------
// Gather: same 32-token blocking as router. Slot = scanned base + ballot rank
// (deterministic). Packs rows into xgT [tile][kc:12][128][64] swizzled bf16.
// ---------------------------------------------------------------------------
__global__ __launch_bounds__(256) void gather2(
    const float* __restrict__ x, const float* __restrict__ tprob,
    const int* __restrict__ be, const int* __restrict__ base_blk,
    bf16* __restrict__ xgT, int* __restrict__ tokmap, float* __restrict__ tpg)
{
  const int tid = threadIdx.x, lane = tid & 63, wv = tid >> 6;
  const int b = blockIdx.x;
  __shared__ int slot_l[32];

  if (wv == 0) {
    const int t = lane;
    const int bet = (t < 32) ? be[b * 32 + t] : -1;
    int slot = -1;
    #pragma unroll
    for (int e = 0; e < NEXP; ++e) {
      unsigned long long msk = __ballot(bet == e);
      if (bet == e) {
        int rank = __popcll(msk & ((1ull << lane) - 1ull));
        slot = base_blk[b * NEXP + e] + rank;
      }
    }
    if (t < 32) {
      slot_l[t] = slot;
      const int tok = b * 32 + t;
      tokmap[slot] = tok;
      tpg[slot] = tprob[tok];
    }
  }
  __syncthreads();

  #pragma unroll 1
  for (int t8 = 0; t8 < 8; ++t8) {
    const int t = wv * 8 + t8;
    const int slot = slot_l[t];
    const int tok = b * 32 + t;
    const int tile = slot >> 7, r = slot & 127;
    #pragma unroll
    for (int j = 0; j < 3; ++j) {
      const int col = j * 256 + lane * 4;
      const int kc = col >> 6, cw = col & 63;
      float4 v = *(const float4*)(x + (size_t)tok * CDIM + col);
      bf16x4 o;
      o[0] = (bf16)v.x; o[1] = (bf16)v.y; o[2] = (bf16)v.z; o[3] = (bf16)v.w;
      char* dst = (char*)xgT + (((size_t)tile * 12 + kc) * 128 + r) * 128
                  + ((cw * 2) ^ ((r & 7) << 4));
      *(bf16x4*)dst = o;
    }
  }
}

// ---------------------------------------------------------------------------
// W [E][R][S] fp32 -> tiled bf16 [E][S/64][R/64][64][64], swizzled rows.
// ---------------------------------------------------------------------------
__global__ __launch_bounds__(256) void transpose_w(
    const float* __restrict__ W, bf16* __restrict__ WT, int R, int S)
{
  __shared__ float t[64][65];
  const int r0 = blockIdx.x * 64, s0 = blockIdx.y * 64, e = blockIdx.z;
  const float* We = W + (size_t)e * R * S;
  const int NT = S >> 6, NK = R >> 6;
  char* outT = (char*)WT + (((size_t)e * NT + (s0 >> 6)) * NK + (r0 >> 6)) * 8192;
  const int tid = threadIdx.x, lr = tid >> 4, lc4 = tid & 15;

  #pragma unroll
  for (int j = 0; j < 4; ++j) {
    int r = lr + j * 16;
    float4 v = *(const float4*)(We + (size_t)(r0 + r) * S + s0 + lc4 * 4);
    t[r][lc4 * 4 + 0] = v.x; t[r][lc4 * 4 + 1] = v.y;
    t[r][lc4 * 4 + 2] = v.z; t[r][lc4 * 4 + 3] = v.w;
  }
  __syncthreads();
  #pragma unroll
  for (int j = 0; j < 4; ++j) {
    int sI = lr + j * 16;
    bf16x4 o;
    #pragma unroll
    for (int q = 0; q < 4; ++q) o[q] = (bf16)t[lc4 * 4 + q][sI];
    *(bf16x4*)(outT + sI * 128 + ((lc4 * 8) ^ ((sI & 7) << 4))) = o;
  }
}

// ---------------------------------------------------------------------------
// FFN1: BM=128, BN=256, BK=64, 4 waves (2x2, per-wave 64x128), single-buffer
// 48 KB LDS -> 3 blocks/CU. 64 MFMA/wave per K-step hides the vmcnt drain.
// ---------------------------------------------------------------------------
__global__ __launch_bounds__(256) void ffn1_k(
    const bf16* __restrict__ Abuf, const bf16* __restrict__ Wt,
    const float* __restrict__ bias, const int* __restrict__ off,
    bf16* __restrict__ hbufT)
{
  const int bid = blockIdx.x + blockIdx.y * 72;     // grid (72,12)
  const int c  = bid & 7;
  const int r2 = bid >> 3;
  const int bx = c * 9 + (r2 % 9);
  const int by = r2 / 9;                            // 0..11

  const int ptot = off[8];
  const int m0 = bx * 128;
  if (m0 >= ptot) return;
  int e = 0;
  #pragma unroll
  for (int q = 0; q < 7; ++q) if (m0 >= off[q + 1]) e = q + 1;

  const int tid = threadIdx.x, lane = tid & 63, wv = tid >> 6;
  const int wr = (wv >> 1) * 64;
  const int wc = (wv & 1) * 128;

  __shared__ __attribute__((aligned(1024))) char smem[49152];
  // A @0 (16K), B @16K (32K: rows 0..255 at 128 B each)

  const char* aBase = (const char*)Abuf + (size_t)bx * 12 * 16384;
  const char* bBase = (const char*)Wt + (((size_t)e * 48 + by * 4 + wv) * 12) * 8192;

  f32x4 acc[4][8];
  #pragma unroll
  for (int i = 0; i < 4; ++i)
    #pragma unroll
    for (int j = 0; j < 8; ++j)
      #pragma unroll
      for (int q = 0; q < 4; ++q) acc[i][j][q] = 0.0f;

  for (int kc = 0; kc < 12; ++kc) {
    __syncthreads();   // previous compute done reading smem
    {
      const char* aS = aBase + (size_t)kc * 16384 + wv * 4096 + lane * 16;
      #pragma unroll
      for (int i = 0; i < 4; ++i)
        load16_lds(aS + i * 1024, smem + wv * 4096 + i * 1024);
      const char* bS = bBase + (size_t)kc * 8192 + lane * 16;
      #pragma unroll
      for (int i = 0; i < 8; ++i)
        load16_lds(bS + i * 1024, smem + 16384 + wv * 8192 + i * 1024);
    }
    __syncthreads();   // vmcnt(0) drain: tile resident
    #pragma unroll
    for (int kk = 0; kk < 2; ++kk) {
      bf16x8 af[4], bfr[8];
      #pragma unroll
      for (int f = 0; f < 4; ++f) {
        int row  = wr + f * 16 + (lane & 15);
        int byte = row * 128 + kk * 64 + (lane >> 4) * 16;
        byte ^= (row & 7) << 4;
        af[f] = *(const bf16x8*)(smem + byte);
      }
      #pragma unroll
      for (int f = 0; f < 8; ++f) {
        int row  = wc + f * 16 + (lane & 15);
        int byte = row * 128 + kk * 64 + (lane >> 4) * 16;
        byte ^= (row & 7) << 4;
        bfr[f] = *(const bf16x8*)(smem + 16384 + byte);
      }
      #pragma unroll
      for (int fm = 0; fm < 4; ++fm)
        #pragma unroll
        for (int fn = 0; fn < 8; ++fn)
          acc[fm][fn] = __builtin_amdgcn_mfma_f32_16x16x32_bf16(
              af[fm], bfr[fn], acc[fm][fn], 0, 0, 0);
    }
  }
  __syncthreads();

  // epilogue: bias + tanh-GELU, two 32 KB passes (C tile is 128x256 = 64 KB)
  const int g = lane >> 4, ci = lane & 15;
  float bv[8];
  #pragma unroll
  for (int fn = 0; fn < 8; ++fn)
    bv[fn] = bias[e * HDIM + by * 256 + wc + fn * 16 + ci];
  char* hdst = (char*)hbufT + ((size_t)bx * 48 + by * 4) * 16384;

  #pragma unroll
  for (int p = 0; p < 2; ++p) {
    if ((wv & 1) == p) {
      #pragma unroll
      for (int fm = 0; fm < 4; ++fm)
        #pragma unroll
        for (int fn = 0; fn < 8; ++fn)
          #pragma unroll
          for (int rg = 0; rg < 4; ++rg) {
            int row  = wr + fm * 16 + g * 4 + rg;
            int col2 = fn * 16 + ci;                 // 0..127 within half
            float v = acc[fm][fn][rg] + bv[fn];
            float t3 = v + 0.044715f * v * v * v;
            float gel = v / (1.0f + __expf(-1.5957691216f * t3));
            int chunk = col2 >> 6, cw = col2 & 63;
            int byte = chunk * 16384 + row * 128 + ((cw * 2) ^ ((row & 7) << 4));
            *(bf16*)(smem + byte) = (bf16)gel;
          }
    }
    __syncthreads();
    #pragma unroll
    for (int i = 0; i < 8; ++i) {
      int bo = (i * 256 + tid) * 16;
      *(f32x4*)(hdst + p * 32768 + bo) = *(const f32x4*)(smem + bo);
    }
    __syncthreads();
  }
}

// ---------------------------------------------------------------------------
// FFN2: BM=128, BN=128, BK=64, 4 waves (2x2, per-wave 64x64), DOUBLE-buffer
// 64 KB LDS with stage-ahead (next tile's loads fly under current MFMA).
// ---------------------------------------------------------------------------
__global__ __launch_bounds__(256, 3) void ffn2_k(
    const bf16* __restrict__ hbufT, const bf16* __restrict__ Wt,
    const float* __restrict__ b2, const int* __restrict__ off,
    const int* __restrict__ tokmap, const float* __restrict__ tpg,
    float* __restrict__ y)
{
  const int bid = blockIdx.x + blockIdx.y * 72;     // grid (72,6)
  const int c  = bid & 7;
  const int r2 = bid >> 3;
  const int bx = c * 9 + (r2 % 9);
  const int by = r2 / 9;                            // 0..5

  const int ptot = off[8];
  const int m0 = bx * 128;
  if (m0 >= ptot) return;
  int e = 0;
  #pragma unroll
  for (int q = 0; q < 7; ++q) if (m0 >= off[q + 1]) e = q + 1;

  const int tid = threadIdx.x, lane = tid & 63, wv = tid >> 6;
  const int wr = (wv >> 1) * 64;
  const int wc = (wv & 1) * 64;

  __shared__ __attribute__((aligned(1024))) char smem[65536];
  // A0 @0, A1 @16K, B0 @32K, B1 @48K

  const char* aBase = (const char*)hbufT + (size_t)bx * 48 * 16384;
  const char* bBase = (const char*)Wt +
      (((size_t)e * 12 + by * 2 + (wv >> 1)) * 48) * 8192 + (wv & 1) * 4096;

  f32x4 acc[4][4];
  #pragma unroll
  for (int i = 0; i < 4; ++i)
    #pragma unroll
    for (int j = 0; j < 4; ++j)
      #pragma unroll
      for (int q = 0; q < 4; ++q) acc[i][j][q] = 0.0f;

  // prologue: stage kc=0 into buf 0
  {
    const char* aS = aBase + wv * 4096 + lane * 16;
    const char* bS = bBase + lane * 16;
    #pragma unroll
    for (int i = 0; i < 4; ++i) {
      load16_lds(aS + i * 1024, smem + wv * 4096 + i * 1024);
      load16_lds(bS + i * 1024, smem + 32768 + wv * 4096 + i * 1024);
    }
  }
  __syncthreads();

  for (int kc = 0; kc < 48; ++kc) {
    const int cur = kc & 1;
    if (kc + 1 < 48) {
      const int nb = cur ^ 1;
      const char* aS = aBase + (size_t)(kc + 1) * 16384 + wv * 4096 + lane * 16;
      const char* bS = bBase + (size_t)(kc + 1) * 8192 + lane * 16;
      #pragma unroll
      for (int i = 0; i < 4; ++i) {
        load16_lds(aS + i * 1024, smem + nb * 16384 + wv * 4096 + i * 1024);
        load16_lds(bS + i * 1024, smem + 32768 + nb * 16384 + wv * 4096 + i * 1024);
      }
    }
    const char* A = smem + cur * 16384;
    const char* B = smem + 32768 + cur * 16384;
    #pragma unroll
    for (int kk = 0; kk < 2; ++kk) {
      bf16x8 af[4], bfr[4];
      #pragma unroll
      for (int f = 0; f < 4; ++f) {
        int row  = wr + f * 16 + (lane & 15);
        int byte = row * 128 + kk * 64 + (lane >> 4) * 16;
        byte ^= (row & 7) << 4;
        af[f] = *(const bf16x8*)(A + byte);
      }
      #pragma unroll
      for (int f = 0; f < 4; ++f) {
        int row  = wc + f * 16 + (lane & 15);
        int byte = row * 128 + kk * 64 + (lane >> 4) * 16;
        byte ^= (row & 7) << 4;
        bfr[f] = *(const bf16x8*)(B + byte);
      }
      #pragma unroll
      for (int fm = 0; fm < 4; ++fm)
        #pragma unroll
        for (int fn = 0; fn < 4; ++fn)
          acc[fm][fn] = __builtin_amdgcn_mfma_f32_16x16x32_bf16(
              af[fm], bfr[fn], acc[fm][fn], 0, 0, 0);
    }
    __syncthreads();   // drains next-tile loads (they flew under the MFMAs)
  }

  // epilogue: bias + tprob -> f32 tile [128][128] (64 KB) -> coalesced scatter
  const int g = lane >> 4, ci = lane & 15;
  float bv[4];
  #pragma unroll
  for (int fn = 0; fn < 4; ++fn)
    bv[fn] = b2[e * CDIM + by * 128 + wc + fn * 16 + ci];
  float tp[4][4];
  #pragma unroll
  for (int fm = 0; fm < 4; ++fm)
    #pragma unroll
    for (int rg = 0; rg < 4; ++rg)
      tp[fm][rg] = tpg[m0 + wr + fm * 16 + g * 4 + rg];

  float* smemf = (float*)smem;
  #pragma unroll
  for (int fm = 0; fm < 4; ++fm)
    #pragma unroll
    for (int fn = 0; fn < 4; ++fn)
      #pragma unroll
      for (int rg = 0; rg < 4; ++rg) {
        int row = wr + fm * 16 + g * 4 + rg;
        int col = wc + fn * 16 + ci;
        smemf[row * 128 + col] = (acc[fm][fn][rg] + bv[fn]) * tp[fm][rg];
      }
  __syncthreads();
  #pragma unroll
  for (int it = 0; it < 16; ++it) {
    int lin = it * 256 + tid;
    int row = lin >> 5;          // 0..127
    int c4  = lin & 31;          // 0..31
    int tokr = tokmap[m0 + row];
    f32x4 v = *(const f32x4*)(smemf + row * 128 + c4 * 4);
    if (tokr >= 0)
      *(f32x4*)(y + (size_t)tokr * CDIM + by * 128 + c4 * 4) = v;
  }
}

// ---------------------------------------------------------------------------
extern "C" void kernel_launch(void* const* d_in, const int* in_sizes, int n_in,
                              void* d_out, int out_size, void* d_ws, size_t ws_size,
                              hipStream_t stream)
{
  const float* x  = (const float*)d_in[0];
  const float* Wr = (const float*)d_in[1];
  const float* W1 = (const float*)d_in[2];
  const float* b1 = (const float*)d_in[3];
  const float* W2 = (const float*)d_in[4];
  const float* b2 = (const float*)d_in[5];
  float* out = (float*)d_out;

  char* ws = (char*)d_ws;
  int*   be         = (int*)(ws + WS_BE);
  float* tprob      = (float*)(ws + WS_TPROB);
  int*   cnt_blk    = (int*)(ws + WS_CNTB);
  float* imp_blk    = (float*)(ws + WS_IMPB);
  int*   base_blk   = (int*)(ws + WS_BASEB);
  int*   counts     = (int*)(ws + WS_CNT);
  int*   off        = (int*)(ws + WS_OFF);
  int*   tokmap     = (int*)(ws + WS_TOKMAP);
  float* tpg        = (float*)(ws + WS_TPG);
  bf16*  xgT        = (bf16*)(ws + WS_XGT);
  bf16*  w1tT       = (bf16*)(ws + WS_W1T);
  bf16*  hbufT      = (bf16*)(ws + WS_HBUF);
  bf16*  w2tT       = (bf16*)(ws + WS_W2T);   // written after ffn1

  hipMemsetAsync(tokmap, 0xFF, 9216 * sizeof(int), stream);

  router3<<<dim3(NBLK), 256, 0, stream>>>(x, Wr, tprob, be, cnt_blk, imp_blk);
  scan_kernel<<<dim3(1), 256, 0, stream>>>(cnt_blk, imp_blk, counts, off,
                                           base_blk, out + (size_t)N_TOK * CDIM);
  gather2<<<dim3(NBLK), 256, 0, stream>>>(x, tprob, be, base_blk,
                                          xgT, tokmap, tpg);
  transpose_w<<<dim3(CDIM / 64, HDIM / 64, NEXP), 256, 0, stream>>>(
      W1, w1tT, CDIM, HDIM);
  ffn1_k<<<dim3(72, 12), 256, 0, stream>>>(xgT, w1tT, b1, off, hbufT);
  transpose_w<<<dim3(HDIM / 64, CDIM / 64, NEXP), 256, 0, stream>>>(
      W2, w2tT, HDIM, CDIM);
  ffn2_k<<<dim3(72, 6), 256, 0, stream>>>(hbufT, w2tT, b2, off,
                                          tokmap, tpg, out);
}

// Round 9
// 176.089 us; speedup vs baseline: 1.4621x; 1.4621x over previous
//
#include <hip/hip_runtime.h>
#include <hip/hip_bf16.h>
#include <cstdint>
#include <cmath>

#define N_TOK 8192
#define CDIM  768
#define HDIM  3072
#define NEXP  8
#define NBLK  256     // router/gather blocks, 32 tokens each

typedef __bf16 bf16;
typedef __bf16 bf16x4 __attribute__((ext_vector_type(4)));
typedef __bf16 bf16x8 __attribute__((ext_vector_type(8)));
typedef float  f32x4  __attribute__((ext_vector_type(4)));

// ws byte offsets
#define WS_BE      0u          // 8192 int
#define WS_TPROB   32768u      // 8192 f32
#define WS_CNTB    65536u      // 256*8 int
#define WS_IMPB    73728u      // 256*8 f32
#define WS_BASEB   81920u      // 256*8 int
#define WS_CNT     90112u      // 8 int
#define WS_OFF     90176u      // 9 int
#define WS_TOKMAP  98304u      // 9216 int
#define WS_TPG     137216u     // 9216 f32  -> ends 174080
#define WS_XGT     (1u<<20)    // 72*12*16384 = 14,155,776
#define WS_W1T     (16u<<20)   // 37,748,736 -> ends 54,525,952
#define WS_HBUF    (56u<<20)   // 72*48*16384 = 56,623,104 -> ends 115,343,360
#define WS_W2T     (1u<<20)    // aliases XGT/W1T, written after ffn1

__device__ __forceinline__ void load16_lds(const void* g, void* l) {
  __builtin_amdgcn_global_load_lds(
      (const __attribute__((address_space(1))) void*)g,
      (__attribute__((address_space(3))) void*)l, 16, 0, 0);
}

// ---------------------------------------------------------------------------
// Router: 256 blocks x 32 tokens, wave-per-token (8 tokens/wave).
// Router weights live in 96 VGPRs per lane. Zero global atomics.
// ---------------------------------------------------------------------------
__global__ __launch_bounds__(256) void router3(
    const float* __restrict__ x, const float* __restrict__ Wr,
    float* __restrict__ tprob, int* __restrict__ be_out,
    int* __restrict__ cnt_blk, float* __restrict__ imp_blk)
{
  const int tid = threadIdx.x, lane = tid & 63, wv = tid >> 6;
  const int b = blockIdx.x;
  __shared__ int cnt_l[NEXP];
  __shared__ float imp_l[4][NEXP];
  if (tid < NEXP) cnt_l[tid] = 0;

  // wreg[j*4+q][e] = Wr[c][e], c = j*256 + lane*4 + q
  float wreg[12][8];
  #pragma unroll
  for (int j = 0; j < 3; ++j)
    #pragma unroll
    for (int q = 0; q < 4; ++q) {
      const float4* p = (const float4*)(Wr + (size_t)(j * 256 + lane * 4 + q) * 8);
      float4 lo = p[0], hi = p[1];
      wreg[j*4+q][0] = lo.x; wreg[j*4+q][1] = lo.y;
      wreg[j*4+q][2] = lo.z; wreg[j*4+q][3] = lo.w;
      wreg[j*4+q][4] = hi.x; wreg[j*4+q][5] = hi.y;
      wreg[j*4+q][6] = hi.z; wreg[j*4+q][7] = hi.w;
    }

  float impacc[NEXP];
  #pragma unroll
  for (int e = 0; e < NEXP; ++e) impacc[e] = 0.0f;
  __syncthreads();

  #pragma unroll 1
  for (int t = 0; t < 8; ++t) {
    const int tok = b * 32 + wv * 8 + t;
    float4 xv[3];
    #pragma unroll
    for (int j = 0; j < 3; ++j)
      xv[j] = *(const float4*)(x + (size_t)tok * CDIM + j * 256 + lane * 4);

    float acc[NEXP];
    #pragma unroll
    for (int e = 0; e < NEXP; ++e) acc[e] = 0.0f;
    #pragma unroll
    for (int j = 0; j < 3; ++j) {
      const float xa[4] = {xv[j].x, xv[j].y, xv[j].z, xv[j].w};
      #pragma unroll
      for (int q = 0; q < 4; ++q)
        #pragma unroll
        for (int e = 0; e < NEXP; ++e)
          acc[e] = fmaf(xa[q], wreg[j*4+q][e], acc[e]);
    }
    #pragma unroll
    for (int e = 0; e < NEXP; ++e) {
      float v = acc[e];
      v += __shfl_xor(v, 1);  v += __shfl_xor(v, 2);  v += __shfl_xor(v, 4);
      v += __shfl_xor(v, 8);  v += __shfl_xor(v, 16); v += __shfl_xor(v, 32);
      acc[e] = v;
    }
    float m = acc[0]; int be = 0;
    #pragma unroll
    for (int e = 1; e < NEXP; ++e) if (acc[e] > m) { m = acc[e]; be = e; }
    float pr[NEXP]; float s = 0.0f;
    #pragma unroll
    for (int e = 0; e < NEXP; ++e) { pr[e] = __expf(acc[e] - m); s += pr[e]; }
    const float inv = 1.0f / s;
    #pragma unroll
    for (int e = 0; e < NEXP; ++e) impacc[e] += pr[e] * inv;
    if (lane == 0) {
      tprob[tok]  = pr[be] * inv;
      be_out[tok] = be;
      atomicAdd(&cnt_l[be], 1);          // LDS atomic
    }
  }

  if (lane == 0) {
    #pragma unroll
    for (int e = 0; e < NEXP; ++e) imp_l[wv][e] = impacc[e];
  }
  __syncthreads();
  if (tid < NEXP) {
    cnt_blk[b * NEXP + tid] = cnt_l[tid];
    imp_blk[b * NEXP + tid] =
        imp_l[0][tid] + imp_l[1][tid] + imp_l[2][tid] + imp_l[3][tid];
  }
}

// ---------------------------------------------------------------------------
// Scan: one block, 256 threads. Per-expert exclusive scan over 256 blocks,
// padded offsets, counts, importance, aux loss. No atomics anywhere.
// ---------------------------------------------------------------------------
__global__ __launch_bounds__(256) void scan_kernel(
    const int* __restrict__ cnt_blk, const float* __restrict__ imp_blk,
    int* __restrict__ counts, int* __restrict__ off,
    int* __restrict__ base_blk, float* __restrict__ out_aux)
{
  const int tid = threadIdx.x, lane = tid & 63, wv = tid >> 6;
  __shared__ int   wsum[NEXP][4];
  __shared__ float wimp[NEXP][4];
  __shared__ int   off_s[9];

  int pref[NEXP];
  #pragma unroll
  for (int e = 0; e < NEXP; ++e) {
    int v = cnt_blk[tid * NEXP + e];
    int inc = v;
    #pragma unroll
    for (int o = 1; o < 64; o <<= 1) {
      int n = __shfl_up(inc, o);
      if (lane >= o) inc += n;
    }
    if (lane == 63) wsum[e][wv] = inc;
    pref[e] = inc - v;

    float f = imp_blk[tid * NEXP + e];
    f += __shfl_xor(f, 1);  f += __shfl_xor(f, 2);  f += __shfl_xor(f, 4);
    f += __shfl_xor(f, 8);  f += __shfl_xor(f, 16); f += __shfl_xor(f, 32);
    if (lane == 0) wimp[e][wv] = f;
  }
  __syncthreads();
  if (tid == 0) {
    int o = 0; float aux = 0.0f;
    #pragma unroll
    for (int e = 0; e < NEXP; ++e) {
      int tot = wsum[e][0] + wsum[e][1] + wsum[e][2] + wsum[e][3];
      float im = wimp[e][0] + wimp[e][1] + wimp[e][2] + wimp[e][3];
      counts[e] = tot;
      aux += im * (float)tot;
      off_s[e] = o;
      o += (tot + 127) & ~127;
    }
    off_s[8] = o;
    out_aux[0] = (float)NEXP * aux / ((float)N_TOK * (float)N_TOK);
    for (int i = 0; i < 9; ++i) off[i] = off_s[i];
  }
  __syncthreads();
  #pragma unroll
  for (int e = 0; e < NEXP; ++e) {
    int wofs = 0;
    #pragma unroll
    for (int w = 0; w < 4; ++w) if (w < wv) wofs += wsum[e][w];
    base_blk[tid * NEXP + e] = off_s[e] + wofs + pref[e];
  }
}

// ---------------------------------------------------------------------------
// Gather: same 32-token blocking as router. Slot = scanned base + ballot rank
// (deterministic). Packs rows into xgT [tile][kc:12][128][64] swizzled bf16.
// ---------------------------------------------------------------------------
__global__ __launch_bounds__(256) void gather2(
    const float* __restrict__ x, const float* __restrict__ tprob,
    const int* __restrict__ be, const int* __restrict__ base_blk,
    bf16* __restrict__ xgT, int* __restrict__ tokmap, float* __restrict__ tpg)
{
  const int tid = threadIdx.x, lane = tid & 63, wv = tid >> 6;
  const int b = blockIdx.x;
  __shared__ int slot_l[32];

  if (wv == 0) {
    const int t = lane;
    const int bet = (t < 32) ? be[b * 32 + t] : -1;
    int slot = -1;
    #pragma unroll
    for (int e = 0; e < NEXP; ++e) {
      unsigned long long msk = __ballot(bet == e);
      if (bet == e) {
        int rank = __popcll(msk & ((1ull << lane) - 1ull));
        slot = base_blk[b * NEXP + e] + rank;
      }
    }
    if (t < 32) {
      slot_l[t] = slot;
      const int tok = b * 32 + t;
      tokmap[slot] = tok;
      tpg[slot] = tprob[tok];
    }
  }
  __syncthreads();

  #pragma unroll 1
  for (int t8 = 0; t8 < 8; ++t8) {
    const int t = wv * 8 + t8;
    const int slot = slot_l[t];
    const int tok = b * 32 + t;
    const int tile = slot >> 7, r = slot & 127;
    #pragma unroll
    for (int j = 0; j < 3; ++j) {
      const int col = j * 256 + lane * 4;
      const int kc = col >> 6, cw = col & 63;
      float4 v = *(const float4*)(x + (size_t)tok * CDIM + col);
      bf16x4 o;
      o[0] = (bf16)v.x; o[1] = (bf16)v.y; o[2] = (bf16)v.z; o[3] = (bf16)v.w;
      char* dst = (char*)xgT + (((size_t)tile * 12 + kc) * 128 + r) * 128
                  + ((cw * 2) ^ ((r & 7) << 4));
      *(bf16x4*)dst = o;
    }
  }
}

// ---------------------------------------------------------------------------
// W [E][R][S] fp32 -> tiled bf16 [E][S/64][R/64][64][64], swizzled rows.
// ---------------------------------------------------------------------------
__global__ __launch_bounds__(256) void transpose_w(
    const float* __restrict__ W, bf16* __restrict__ WT, int R, int S)
{
  __shared__ float t[64][65];
  const int r0 = blockIdx.x * 64, s0 = blockIdx.y * 64, e = blockIdx.z;
  const float* We = W + (size_t)e * R * S;
  const int NT = S >> 6, NK = R >> 6;
  char* outT = (char*)WT + (((size_t)e * NT + (s0 >> 6)) * NK + (r0 >> 6)) * 8192;
  const int tid = threadIdx.x, lr = tid >> 4, lc4 = tid & 15;

  #pragma unroll
  for (int j = 0; j < 4; ++j) {
    int r = lr + j * 16;
    float4 v = *(const float4*)(We + (size_t)(r0 + r) * S + s0 + lc4 * 4);
    t[r][lc4 * 4 + 0] = v.x; t[r][lc4 * 4 + 1] = v.y;
    t[r][lc4 * 4 + 2] = v.z; t[r][lc4 * 4 + 3] = v.w;
  }
  __syncthreads();
  #pragma unroll
  for (int j = 0; j < 4; ++j) {
    int sI = lr + j * 16;
    bf16x4 o;
    #pragma unroll
    for (int q = 0; q < 4; ++q) o[q] = (bf16)t[lc4 * 4 + q][sI];
    *(bf16x4*)(outT + sI * 128 + ((lc4 * 8) ^ ((sI & 7) << 4))) = o;
  }
}

// ---------------------------------------------------------------------------
// Grouped GEMM with counted-vmcnt depth-2 pipeline (T3/T4 minimal form):
// BM=128, BN=128, BK=64, 4 waves (2x2, per-wave 64x64), 2 LDS buffers (64 KB).
// Per iter: barrier -> ds_read buf(k) -> lgkmcnt(0)+sched_barrier -> barrier
//   -> stage buf(k) <- tile k+2 (freed space) -> 32 MFMA -> vmcnt(8).
// vmcnt never drains to 0 in steady state; tile k+2's loads stay in flight.
// ---------------------------------------------------------------------------
template<int NKC, int NCHN, bool GELU>
__global__ __launch_bounds__(256, 2) void ffn_p(
    const bf16* __restrict__ Abuf, const bf16* __restrict__ Wt,
    const float* __restrict__ bias, const int* __restrict__ off,
    const int* __restrict__ tokmap, const float* __restrict__ tpg,
    bf16* __restrict__ hbufT, float* __restrict__ y)
{
  const int bid = blockIdx.x + blockIdx.y * 72;
  const int c  = bid & 7;
  const int r2 = bid >> 3;
  const int bx = c * 9 + (r2 % 9);
  const int by = r2 / 9;

  const int ptot = off[8];
  const int m0 = bx * 128;
  if (m0 >= ptot) return;
  int e = 0;
  #pragma unroll
  for (int q = 0; q < 7; ++q) if (m0 >= off[q + 1]) e = q + 1;

  const int tid = threadIdx.x, lane = tid & 63, wv = tid >> 6;
  const int wr = (wv >> 1) * 64;
  const int wc = (wv & 1) * 64;

  __shared__ __attribute__((aligned(1024))) char smem[65536];
  // buffer b at b*32768: A 16K @ +0, B 16K @ +16K

  const char* aBase = (const char*)Abuf + (size_t)bx * NKC * 16384;
  const char* bBase = (const char*)Wt +
      (((size_t)e * NCHN + by * 2 + (wv >> 1)) * NKC) * 8192 + (wv & 1) * 4096;

  auto stage = [&](int buf, int kc) {
    const char* aS = aBase + (size_t)kc * 16384 + wv * 4096 + lane * 16;
    const char* bS = bBase + (size_t)kc * 8192 + lane * 16;
    char* ab = smem + buf * 32768;
    #pragma unroll
    for (int i = 0; i < 4; ++i) {
      load16_lds(aS + i * 1024, ab + wv * 4096 + i * 1024);
      load16_lds(bS + i * 1024, ab + 16384 + wv * 4096 + i * 1024);
    }
  };

  f32x4 acc[4][4];
  #pragma unroll
  for (int i = 0; i < 4; ++i)
    #pragma unroll
    for (int j = 0; j < 4; ++j)
      #pragma unroll
      for (int q = 0; q < 4; ++q) acc[i][j][q] = 0.0f;

  // prologue: 2 tiles in flight, wait only for tile 0 (8 of 16 outstanding)
  stage(0, 0);
  stage(1, 1);
  asm volatile("s_waitcnt vmcnt(8)" ::: "memory");

  for (int kc = 0; kc < NKC; ++kc) {
    const int cur = kc & 1;
    __builtin_amdgcn_s_barrier();          // buf(cur) resident in all waves
    const char* A = smem + cur * 32768;
    const char* B = A + 16384;
    bf16x8 af[2][4], bfr[2][4];
    #pragma unroll
    for (int kk = 0; kk < 2; ++kk) {
      #pragma unroll
      for (int f = 0; f < 4; ++f) {
        int row  = wr + f * 16 + (lane & 15);
        int byte = row * 128 + kk * 64 + (lane >> 4) * 16;
        byte ^= (row & 7) << 4;
        af[kk][f] = *(const bf16x8*)(A + byte);
      }
      #pragma unroll
      for (int f = 0; f < 4; ++f) {
        int row  = wc + f * 16 + (lane & 15);
        int byte = row * 128 + kk * 64 + (lane >> 4) * 16;
        byte ^= (row & 7) << 4;
        bfr[kk][f] = *(const bf16x8*)(B + byte);
      }
    }
    asm volatile("s_waitcnt lgkmcnt(0)" ::: "memory");
    __builtin_amdgcn_sched_barrier(0);     // rule #18: pin reads before barrier
    __builtin_amdgcn_s_barrier();          // all waves done reading buf(cur)
    if (kc + 2 < NKC) stage(cur, kc + 2);  // refill freed buffer, depth-2
    #pragma unroll
    for (int kk = 0; kk < 2; ++kk)
      #pragma unroll
      for (int fm = 0; fm < 4; ++fm)
        #pragma unroll
        for (int fn = 0; fn < 4; ++fn)
          acc[fm][fn] = __builtin_amdgcn_mfma_f32_16x16x32_bf16(
              af[kk][fm], bfr[kk][fn], acc[fm][fn], 0, 0, 0);
    if (kc + 1 < NKC) {
      if (kc + 2 < NKC)
        asm volatile("s_waitcnt vmcnt(8)" ::: "memory");  // k+1 done, k+2 flies
      else
        asm volatile("s_waitcnt vmcnt(0)" ::: "memory");  // tail drain
    }
  }
  __syncthreads();     // epilogue reuses smem

  const int g = lane >> 4, ci = lane & 15;
  float bv[4];
  #pragma unroll
  for (int fn = 0; fn < 4; ++fn)
    bv[fn] = bias[e * (NCHN * 64) + by * 128 + wc + fn * 16 + ci];

  if (GELU) {
    // bias + tanh-GELU -> swizzled bf16 C tile (32 KB) -> linear copy to hbufT
    #pragma unroll
    for (int fm = 0; fm < 4; ++fm)
      #pragma unroll
      for (int fn = 0; fn < 4; ++fn)
        #pragma unroll
        for (int rg = 0; rg < 4; ++rg) {
          int row = wr + fm * 16 + g * 4 + rg;
          int col = wc + fn * 16 + ci;
          float v = acc[fm][fn][rg] + bv[fn];
          float t3 = v + 0.044715f * v * v * v;
          float gel = v / (1.0f + __expf(-1.5957691216f * t3));
          int chunk = col >> 6, cw = col & 63;
          int byte = chunk * 16384 + row * 128 + ((cw * 2) ^ ((row & 7) << 4));
          *(bf16*)(smem + byte) = (bf16)gel;
        }
    __syncthreads();
    char* hdst = (char*)hbufT + ((size_t)bx * 48 + by * 2) * 16384;
    #pragma unroll
    for (int i = 0; i < 8; ++i) {
      int bo = (i * 256 + tid) * 16;
      *(f32x4*)(hdst + bo) = *(const f32x4*)(smem + bo);
    }
  } else {
    // bias + tprob -> f32 tile [128][128] (64 KB) -> coalesced row scatter
    float tp[4][4];
    #pragma unroll
    for (int fm = 0; fm < 4; ++fm)
      #pragma unroll
      for (int rg = 0; rg < 4; ++rg)
        tp[fm][rg] = tpg[m0 + wr + fm * 16 + g * 4 + rg];
    float* smemf = (float*)smem;
    #pragma unroll
    for (int fm = 0; fm < 4; ++fm)
      #pragma unroll
      for (int fn = 0; fn < 4; ++fn)
        #pragma unroll
        for (int rg = 0; rg < 4; ++rg) {
          int row = wr + fm * 16 + g * 4 + rg;
          int col = wc + fn * 16 + ci;
          smemf[row * 128 + col] = (acc[fm][fn][rg] + bv[fn]) * tp[fm][rg];
        }
    __syncthreads();
    #pragma unroll
    for (int it = 0; it < 16; ++it) {
      int lin = it * 256 + tid;
      int row = lin >> 5;          // 0..127
      int c4  = lin & 31;          // 0..31
      int tokr = tokmap[m0 + row];
      f32x4 v = *(const f32x4*)(smemf + row * 128 + c4 * 4);
      if (tokr >= 0)
        *(f32x4*)(y + (size_t)tokr * CDIM + by * 128 + c4 * 4) = v;
    }
  }
}

// ---------------------------------------------------------------------------
extern "C" void kernel_launch(void* const* d_in, const int* in_sizes, int n_in,
                              void* d_out, int out_size, void* d_ws, size_t ws_size,
                              hipStream_t stream)
{
  const float* x  = (const float*)d_in[0];
  const float* Wr = (const float*)d_in[1];
  const float* W1 = (const float*)d_in[2];
  const float* b1 = (const float*)d_in[3];
  const float* W2 = (const float*)d_in[4];
  const float* b2 = (const float*)d_in[5];
  float* out = (float*)d_out;

  char* ws = (char*)d_ws;
  int*   be         = (int*)(ws + WS_BE);
  float* tprob      = (float*)(ws + WS_TPROB);
  int*   cnt_blk    = (int*)(ws + WS_CNTB);
  float* imp_blk    = (float*)(ws + WS_IMPB);
  int*   base_blk   = (int*)(ws + WS_BASEB);
  int*   counts     = (int*)(ws + WS_CNT);
  int*   off        = (int*)(ws + WS_OFF);
  int*   tokmap     = (int*)(ws + WS_TOKMAP);
  float* tpg        = (float*)(ws + WS_TPG);
  bf16*  xgT        = (bf16*)(ws + WS_XGT);
  bf16*  w1tT       = (bf16*)(ws + WS_W1T);
  bf16*  hbufT      = (bf16*)(ws + WS_HBUF);
  bf16*  w2tT       = (bf16*)(ws + WS_W2T);   // written after ffn1

  hipMemsetAsync(tokmap, 0xFF, 9216 * sizeof(int), stream);

  router3<<<dim3(NBLK), 256, 0, stream>>>(x, Wr, tprob, be, cnt_blk, imp_blk);
  scan_kernel<<<dim3(1), 256, 0, stream>>>(cnt_blk, imp_blk, counts, off,
                                           base_blk, out + (size_t)N_TOK * CDIM);
  gather2<<<dim3(NBLK), 256, 0, stream>>>(x, tprob, be, base_blk,
                                          xgT, tokmap, tpg);
  transpose_w<<<dim3(CDIM / 64, HDIM / 64, NEXP), 256, 0, stream>>>(
      W1, w1tT, CDIM, HDIM);
  ffn_p<12, 48, true><<<dim3(72, 24), 256, 0, stream>>>(
      xgT, w1tT, b1, off, nullptr, nullptr, hbufT, nullptr);
  transpose_w<<<dim3(HDIM / 64, CDIM / 64, NEXP), 256, 0, stream>>>(
      W2, w2tT, HDIM, CDIM);
  ffn_p<48, 12, false><<<dim3(72, 6), 256, 0, stream>>>(
      hbufT, w2tT, b2, off, tokmap, tpg, nullptr, out);
}

// Round 10
// 172.896 us; speedup vs baseline: 1.4891x; 1.0185x over previous
//
#include <hip/hip_runtime.h>
#include <hip/hip_bf16.h>
#include <cstdint>
#include <cmath>

#define N_TOK 8192
#define CDIM  768
#define HDIM  3072
#define NEXP  8
#define NBLK  256     // router/gather blocks, 32 tokens each

typedef __bf16 bf16;
typedef __bf16 bf16x4 __attribute__((ext_vector_type(4)));
typedef __bf16 bf16x8 __attribute__((ext_vector_type(8)));
typedef float  f32x4  __attribute__((ext_vector_type(4)));

// ws byte offsets
#define WS_BE      0u          // 8192 int
#define WS_TPROB   32768u      // 8192 f32
#define WS_CNTB    65536u      // 256*8 int
#define WS_IMPB    73728u      // 256*8 f32
#define WS_BASEB   81920u      // 256*8 int
#define WS_CNT     90112u      // 8 int
#define WS_OFF     90176u      // 9 int
#define WS_TOKMAP  98304u      // 9216 int
#define WS_TPG     137216u     // 9216 f32  -> ends 174080
#define WS_XGT     (1u<<20)    // 72*12*16384 = 14,155,776
#define WS_W1T     (16u<<20)   // 37,748,736 -> ends 54,525,952
#define WS_HBUF    (56u<<20)   // 72*48*16384 = 56,623,104 -> ends 115,343,360
#define WS_W2T     (1u<<20)    // aliases XGT/W1T, written after ffn1

__device__ __forceinline__ void load16_lds(const void* g, void* l) {
  __builtin_amdgcn_global_load_lds(
      (const __attribute__((address_space(1))) void*)g,
      (__attribute__((address_space(3))) void*)l, 16, 0, 0);
}

// ---------------------------------------------------------------------------
// Router: 256 blocks x 32 tokens, wave-per-token (8 tokens/wave).
// Router weights live in 96 VGPRs per lane. Zero global atomics.
// ---------------------------------------------------------------------------
__global__ __launch_bounds__(256) void router3(
    const float* __restrict__ x, const float* __restrict__ Wr,
    float* __restrict__ tprob, int* __restrict__ be_out,
    int* __restrict__ cnt_blk, float* __restrict__ imp_blk)
{
  const int tid = threadIdx.x, lane = tid & 63, wv = tid >> 6;
  const int b = blockIdx.x;
  __shared__ int cnt_l[NEXP];
  __shared__ float imp_l[4][NEXP];
  if (tid < NEXP) cnt_l[tid] = 0;

  // wreg[j*4+q][e] = Wr[c][e], c = j*256 + lane*4 + q
  float wreg[12][8];
  #pragma unroll
  for (int j = 0; j < 3; ++j)
    #pragma unroll
    for (int q = 0; q < 4; ++q) {
      const float4* p = (const float4*)(Wr + (size_t)(j * 256 + lane * 4 + q) * 8);
      float4 lo = p[0], hi = p[1];
      wreg[j*4+q][0] = lo.x; wreg[j*4+q][1] = lo.y;
      wreg[j*4+q][2] = lo.z; wreg[j*4+q][3] = lo.w;
      wreg[j*4+q][4] = hi.x; wreg[j*4+q][5] = hi.y;
      wreg[j*4+q][6] = hi.z; wreg[j*4+q][7] = hi.w;
    }

  float impacc[NEXP];
  #pragma unroll
  for (int e = 0; e < NEXP; ++e) impacc[e] = 0.0f;
  __syncthreads();

  #pragma unroll 1
  for (int t = 0; t < 8; ++t) {
    const int tok = b * 32 + wv * 8 + t;
    float4 xv[3];
    #pragma unroll
    for (int j = 0; j < 3; ++j)
      xv[j] = *(const float4*)(x + (size_t)tok * CDIM + j * 256 + lane * 4);

    float acc[NEXP];
    #pragma unroll
    for (int e = 0; e < NEXP; ++e) acc[e] = 0.0f;
    #pragma unroll
    for (int j = 0; j < 3; ++j) {
      const float xa[4] = {xv[j].x, xv[j].y, xv[j].z, xv[j].w};
      #pragma unroll
      for (int q = 0; q < 4; ++q)
        #pragma unroll
        for (int e = 0; e < NEXP; ++e)
          acc[e] = fmaf(xa[q], wreg[j*4+q][e], acc[e]);
    }
    #pragma unroll
    for (int e = 0; e < NEXP; ++e) {
      float v = acc[e];
      v += __shfl_xor(v, 1);  v += __shfl_xor(v, 2);  v += __shfl_xor(v, 4);
      v += __shfl_xor(v, 8);  v += __shfl_xor(v, 16); v += __shfl_xor(v, 32);
      acc[e] = v;
    }
    float m = acc[0]; int be = 0;
    #pragma unroll
    for (int e = 1; e < NEXP; ++e) if (acc[e] > m) { m = acc[e]; be = e; }
    float pr[NEXP]; float s = 0.0f;
    #pragma unroll
    for (int e = 0; e < NEXP; ++e) { pr[e] = __expf(acc[e] - m); s += pr[e]; }
    const float inv = 1.0f / s;
    #pragma unroll
    for (int e = 0; e < NEXP; ++e) impacc[e] += pr[e] * inv;
    if (lane == 0) {
      tprob[tok]  = pr[be] * inv;
      be_out[tok] = be;
      atomicAdd(&cnt_l[be], 1);          // LDS atomic
    }
  }

  if (lane == 0) {
    #pragma unroll
    for (int e = 0; e < NEXP; ++e) imp_l[wv][e] = impacc[e];
  }
  __syncthreads();
  if (tid < NEXP) {
    cnt_blk[b * NEXP + tid] = cnt_l[tid];
    imp_blk[b * NEXP + tid] =
        imp_l[0][tid] + imp_l[1][tid] + imp_l[2][tid] + imp_l[3][tid];
  }
}

// ---------------------------------------------------------------------------
// Scan: one block, 256 threads. Per-expert exclusive scan over 256 blocks,
// padded offsets, counts, importance, aux loss. Also fills pad tokmap = -1
// (replaces the hipMemsetAsync launch). No atomics anywhere.
// ---------------------------------------------------------------------------
__global__ __launch_bounds__(256) void scan_kernel(
    const int* __restrict__ cnt_blk, const float* __restrict__ imp_blk,
    int* __restrict__ counts, int* __restrict__ off,
    int* __restrict__ base_blk, float* __restrict__ out_aux,
    int* __restrict__ tokmap)
{
  const int tid = threadIdx.x, lane = tid & 63, wv = tid >> 6;
  __shared__ int   wsum[NEXP][4];
  __shared__ float wimp[NEXP][4];
  __shared__ int   off_s[9];
  __shared__ int   cnt_s[NEXP];

  int pref[NEXP];
  #pragma unroll
  for (int e = 0; e < NEXP; ++e) {
    int v = cnt_blk[tid * NEXP + e];
    int inc = v;
    #pragma unroll
    for (int o = 1; o < 64; o <<= 1) {
      int n = __shfl_up(inc, o);
      if (lane >= o) inc += n;
    }
    if (lane == 63) wsum[e][wv] = inc;
    pref[e] = inc - v;

    float f = imp_blk[tid * NEXP + e];
    f += __shfl_xor(f, 1);  f += __shfl_xor(f, 2);  f += __shfl_xor(f, 4);
    f += __shfl_xor(f, 8);  f += __shfl_xor(f, 16); f += __shfl_xor(f, 32);
    if (lane == 0) wimp[e][wv] = f;
  }
  __syncthreads();
  if (tid == 0) {
    int o = 0; float aux = 0.0f;
    #pragma unroll
    for (int e = 0; e < NEXP; ++e) {
      int tot = wsum[e][0] + wsum[e][1] + wsum[e][2] + wsum[e][3];
      float im = wimp[e][0] + wimp[e][1] + wimp[e][2] + wimp[e][3];
      counts[e] = tot;
      cnt_s[e] = tot;
      aux += im * (float)tot;
      off_s[e] = o;
      o += (tot + 127) & ~127;
    }
    off_s[8] = o;
    out_aux[0] = (float)NEXP * aux / ((float)N_TOK * (float)N_TOK);
    for (int i = 0; i < 9; ++i) off[i] = off_s[i];
  }
  __syncthreads();
  #pragma unroll
  for (int e = 0; e < NEXP; ++e) {
    int wofs = 0;
    #pragma unroll
    for (int w = 0; w < 4; ++w) if (w < wv) wofs += wsum[e][w];
    base_blk[tid * NEXP + e] = off_s[e] + wofs + pref[e];
  }
  // pad slots: tokmap = -1 so ffn2's scatter skips them
  #pragma unroll 1
  for (int e = 0; e < NEXP; ++e) {
    int p0 = off_s[e] + cnt_s[e], p1 = off_s[e + 1];
    for (int i = p0 + tid; i < p1; i += 256) tokmap[i] = -1;
  }
}

// ---------------------------------------------------------------------------
// Gather: same 32-token blocking as router. Slot = scanned base + ballot rank
// (deterministic). Packs rows into xgT [tile][kc:12][128][64] swizzled bf16.
// ---------------------------------------------------------------------------
__global__ __launch_bounds__(256) void gather2(
    const float* __restrict__ x, const float* __restrict__ tprob,
    const int* __restrict__ be, const int* __restrict__ base_blk,
    bf16* __restrict__ xgT, int* __restrict__ tokmap, float* __restrict__ tpg)
{
  const int tid = threadIdx.x, lane = tid & 63, wv = tid >> 6;
  const int b = blockIdx.x;
  __shared__ int slot_l[32];

  if (wv == 0) {
    const int t = lane;
    const int bet = (t < 32) ? be[b * 32 + t] : -1;
    int slot = -1;
    #pragma unroll
    for (int e = 0; e < NEXP; ++e) {
      unsigned long long msk = __ballot(bet == e);
      if (bet == e) {
        int rank = __popcll(msk & ((1ull << lane) - 1ull));
        slot = base_blk[b * NEXP + e] + rank;
      }
    }
    if (t < 32) {
      slot_l[t] = slot;
      const int tok = b * 32 + t;
      tokmap[slot] = tok;
      tpg[slot] = tprob[tok];
    }
  }
  __syncthreads();

  #pragma unroll 1
  for (int t8 = 0; t8 < 8; ++t8) {
    const int t = wv * 8 + t8;
    const int slot = slot_l[t];
    const int tok = b * 32 + t;
    const int tile = slot >> 7, r = slot & 127;
    #pragma unroll
    for (int j = 0; j < 3; ++j) {
      const int col = j * 256 + lane * 4;
      const int kc = col >> 6, cw = col & 63;
      float4 v = *(const float4*)(x + (size_t)tok * CDIM + col);
      bf16x4 o;
      o[0] = (bf16)v.x; o[1] = (bf16)v.y; o[2] = (bf16)v.z; o[3] = (bf16)v.w;
      char* dst = (char*)xgT + (((size_t)tile * 12 + kc) * 128 + r) * 128
                  + ((cw * 2) ^ ((r & 7) << 4));
      *(bf16x4*)dst = o;
    }
  }
}

// ---------------------------------------------------------------------------
// W [E][R][S] fp32 -> tiled bf16 [E][S/64][R/64][64][64], swizzled rows.
// ---------------------------------------------------------------------------
__global__ __launch_bounds__(256) void transpose_w(
    const float* __restrict__ W, bf16* __restrict__ WT, int R, int S)
{
  __shared__ float t[64][65];
  const int r0 = blockIdx.x * 64, s0 = blockIdx.y * 64, e = blockIdx.z;
  const float* We = W + (size_t)e * R * S;
  const int NT = S >> 6, NK = R >> 6;
  char* outT = (char*)WT + (((size_t)e * NT + (s0 >> 6)) * NK + (r0 >> 6)) * 8192;
  const int tid = threadIdx.x, lr = tid >> 4, lc4 = tid & 15;

  #pragma unroll
  for (int j = 0; j < 4; ++j) {
    int r = lr + j * 16;
    float4 v = *(const float4*)(We + (size_t)(r0 + r) * S + s0 + lc4 * 4);
    t[r][lc4 * 4 + 0] = v.x; t[r][lc4 * 4 + 1] = v.y;
    t[r][lc4 * 4 + 2] = v.z; t[r][lc4 * 4 + 3] = v.w;
  }
  __syncthreads();
  #pragma unroll
  for (int j = 0; j < 4; ++j) {
    int sI = lr + j * 16;
    bf16x4 o;
    #pragma unroll
    for (int q = 0; q < 4; ++q) o[q] = (bf16)t[lc4 * 4 + q][sI];
    *(bf16x4*)(outT + sI * 128 + ((lc4 * 8) ^ ((sI & 7) << 4))) = o;
  }
}

// ---------------------------------------------------------------------------
// Grouped GEMM, counted-vmcnt depth-2 pipeline. BM=128, BN=128, BK=64,
// 4 waves (2x2, per-wave 64x64), 2 LDS buffers (64 KB).
// This round: hoisted swizzled ds_read offsets, MFMA split into 2 clusters
// with the vmcnt(8) wait between them, s_setprio(1) around each cluster.
// ---------------------------------------------------------------------------
template<int NKC, int NCHN, bool GELU>
__global__ __launch_bounds__(256, 2) void ffn_p(
    const bf16* __restrict__ Abuf, const bf16* __restrict__ Wt,
    const float* __restrict__ bias, const int* __restrict__ off,
    const int* __restrict__ tokmap, const float* __restrict__ tpg,
    bf16* __restrict__ hbufT, float* __restrict__ y)
{
  const int bid = blockIdx.x + blockIdx.y * 72;
  const int c  = bid & 7;
  const int r2 = bid >> 3;
  const int bx = c * 9 + (r2 % 9);
  const int by = r2 / 9;

  const int ptot = off[8];
  const int m0 = bx * 128;
  if (m0 >= ptot) return;
  int e = 0;
  #pragma unroll
  for (int q = 0; q < 7; ++q) if (m0 >= off[q + 1]) e = q + 1;

  const int tid = threadIdx.x, lane = tid & 63, wv = tid >> 6;
  const int wr = (wv >> 1) * 64;
  const int wc = (wv & 1) * 64;

  __shared__ __attribute__((aligned(1024))) char smem[65536];
  // buffer b at b*32768: A 16K @ +0, B 16K @ +16K

  const char* aBase = (const char*)Abuf + (size_t)bx * NKC * 16384;
  const char* bBase = (const char*)Wt +
      (((size_t)e * NCHN + by * 2 + (wv >> 1)) * NKC) * 8192 + (wv & 1) * 4096;

  auto stage = [&](int buf, int kc) {
    const char* aS = aBase + (size_t)kc * 16384 + wv * 4096 + lane * 16;
    const char* bS = bBase + (size_t)kc * 8192 + lane * 16;
    char* ab = smem + buf * 32768;
    #pragma unroll
    for (int i = 0; i < 4; ++i) {
      load16_lds(aS + i * 1024, ab + wv * 4096 + i * 1024);
      load16_lds(bS + i * 1024, ab + 16384 + wv * 4096 + i * 1024);
    }
  };

  // hoisted swizzled byte offsets (lane-constant across the K-loop)
  int aoff[2][4], boff[2][4];
  #pragma unroll
  for (int kk = 0; kk < 2; ++kk)
    #pragma unroll
    for (int f = 0; f < 4; ++f) {
      int rowA = wr + f * 16 + (lane & 15);
      int ba   = rowA * 128 + kk * 64 + (lane >> 4) * 16;
      aoff[kk][f] = ba ^ ((rowA & 7) << 4);
      int rowB = wc + f * 16 + (lane & 15);
      int bb   = rowB * 128 + kk * 64 + (lane >> 4) * 16;
      boff[kk][f] = bb ^ ((rowB & 7) << 4);
    }

  f32x4 acc[4][4];
  #pragma unroll
  for (int i = 0; i < 4; ++i)
    #pragma unroll
    for (int j = 0; j < 4; ++j)
      #pragma unroll
      for (int q = 0; q < 4; ++q) acc[i][j][q] = 0.0f;

  // prologue: 2 tiles in flight, wait only for tile 0 (8 of 16 outstanding)
  stage(0, 0);
  stage(1, 1);
  asm volatile("s_waitcnt vmcnt(8)" ::: "memory");

  for (int kc = 0; kc < NKC; ++kc) {
    const int cur = kc & 1;
    __builtin_amdgcn_s_barrier();          // buf(cur) resident in all waves
    const char* A = smem + cur * 32768;
    const char* B = A + 16384;
    bf16x8 af[2][4], bfr[2][4];
    #pragma unroll
    for (int kk = 0; kk < 2; ++kk) {
      #pragma unroll
      for (int f = 0; f < 4; ++f) af[kk][f]  = *(const bf16x8*)(A + aoff[kk][f]);
      #pragma unroll
      for (int f = 0; f < 4; ++f) bfr[kk][f] = *(const bf16x8*)(B + boff[kk][f]);
    }
    asm volatile("s_waitcnt lgkmcnt(0)" ::: "memory");
    __builtin_amdgcn_sched_barrier(0);     // rule #18: pin reads before barrier
    __builtin_amdgcn_s_barrier();          // all waves done reading buf(cur)
    if (kc + 2 < NKC) stage(cur, kc + 2);  // refill freed buffer, depth-2

    __builtin_amdgcn_s_setprio(1);
    #pragma unroll
    for (int fm = 0; fm < 4; ++fm)
      #pragma unroll
      for (int fn = 0; fn < 4; ++fn)
        acc[fm][fn] = __builtin_amdgcn_mfma_f32_16x16x32_bf16(
            af[0][fm], bfr[0][fn], acc[fm][fn], 0, 0, 0);
    __builtin_amdgcn_s_setprio(0);

    if (kc + 1 < NKC) {
      __builtin_amdgcn_sched_barrier(0);
      if (kc + 2 < NKC)
        asm volatile("s_waitcnt vmcnt(8)" ::: "memory");  // k+1 done, k+2 flies
      else
        asm volatile("s_waitcnt vmcnt(0)" ::: "memory");  // tail drain
      __builtin_amdgcn_sched_barrier(0);
    }

    __builtin_amdgcn_s_setprio(1);
    #pragma unroll
    for (int fm = 0; fm < 4; ++fm)
      #pragma unroll
      for (int fn = 0; fn < 4; ++fn)
        acc[fm][fn] = __builtin_amdgcn_mfma_f32_16x16x32_bf16(
            af[1][fm], bfr[1][fn], acc[fm][fn], 0, 0, 0);
    __builtin_amdgcn_s_setprio(0);
  }
  __syncthreads();     // epilogue reuses smem

  const int g = lane >> 4, ci = lane & 15;
  float bv[4];
  #pragma unroll
  for (int fn = 0; fn < 4; ++fn)
    bv[fn] = bias[e * (NCHN * 64) + by * 128 + wc + fn * 16 + ci];

  if (GELU) {
    // bias + tanh-GELU -> swizzled bf16 C tile (32 KB) -> linear copy to hbufT
    #pragma unroll
    for (int fm = 0; fm < 4; ++fm)
      #pragma unroll
      for (int fn = 0; fn < 4; ++fn)
        #pragma unroll
        for (int rg = 0; rg < 4; ++rg) {
          int row = wr + fm * 16 + g * 4 + rg;
          int col = wc + fn * 16 + ci;
          float v = acc[fm][fn][rg] + bv[fn];
          float t3 = v + 0.044715f * v * v * v;
          float gel = v / (1.0f + __expf(-1.5957691216f * t3));
          int chunk = col >> 6, cw = col & 63;
          int byte = chunk * 16384 + row * 128 + ((cw * 2) ^ ((row & 7) << 4));
          *(bf16*)(smem + byte) = (bf16)gel;
        }
    __syncthreads();
    char* hdst = (char*)hbufT + ((size_t)bx * 48 + by * 2) * 16384;
    #pragma unroll
    for (int i = 0; i < 8; ++i) {
      int bo = (i * 256 + tid) * 16;
      *(f32x4*)(hdst + bo) = *(const f32x4*)(smem + bo);
    }
  } else {
    // bias + tprob -> f32 tile [128][128] (64 KB) -> coalesced row scatter
    float tp[4][4];
    #pragma unroll
    for (int fm = 0; fm < 4; ++fm)
      #pragma unroll
      for (int rg = 0; rg < 4; ++rg)
        tp[fm][rg] = tpg[m0 + wr + fm * 16 + g * 4 + rg];
    float* smemf = (float*)smem;
    #pragma unroll
    for (int fm = 0; fm < 4; ++fm)
      #pragma unroll
      for (int fn = 0; fn < 4; ++fn)
        #pragma unroll
        for (int rg = 0; rg < 4; ++rg) {
          int row = wr + fm * 16 + g * 4 + rg;
          int col = wc + fn * 16 + ci;
          smemf[row * 128 + col] = (acc[fm][fn][rg] + bv[fn]) * tp[fm][rg];
        }
    __syncthreads();
    #pragma unroll
    for (int it = 0; it < 16; ++it) {
      int lin = it * 256 + tid;
      int row = lin >> 5;          // 0..127
      int c4  = lin & 31;          // 0..31
      int tokr = tokmap[m0 + row];
      f32x4 v = *(const f32x4*)(smemf + row * 128 + c4 * 4);
      if (tokr >= 0)
        *(f32x4*)(y + (size_t)tokr * CDIM + by * 128 + c4 * 4) = v;
    }
  }
}

// ---------------------------------------------------------------------------
extern "C" void kernel_launch(void* const* d_in, const int* in_sizes, int n_in,
                              void* d_out, int out_size, void* d_ws, size_t ws_size,
                              hipStream_t stream)
{
  const float* x  = (const float*)d_in[0];
  const float* Wr = (const float*)d_in[1];
  const float* W1 = (const float*)d_in[2];
  const float* b1 = (const float*)d_in[3];
  const float* W2 = (const float*)d_in[4];
  const float* b2 = (const float*)d_in[5];
  float* out = (float*)d_out;

  char* ws = (char*)d_ws;
  int*   be         = (int*)(ws + WS_BE);
  float* tprob      = (float*)(ws + WS_TPROB);
  int*   cnt_blk    = (int*)(ws + WS_CNTB);
  float* imp_blk    = (float*)(ws + WS_IMPB);
  int*   base_blk   = (int*)(ws + WS_BASEB);
  int*   counts     = (int*)(ws + WS_CNT);
  int*   off        = (int*)(ws + WS_OFF);
  int*   tokmap     = (int*)(ws + WS_TOKMAP);
  float* tpg        = (float*)(ws + WS_TPG);
  bf16*  xgT        = (bf16*)(ws + WS_XGT);
  bf16*  w1tT       = (bf16*)(ws + WS_W1T);
  bf16*  hbufT      = (bf16*)(ws + WS_HBUF);
  bf16*  w2tT       = (bf16*)(ws + WS_W2T);   // written after ffn1

  router3<<<dim3(NBLK), 256, 0, stream>>>(x, Wr, tprob, be, cnt_blk, imp_blk);
  scan_kernel<<<dim3(1), 256, 0, stream>>>(cnt_blk, imp_blk, counts, off,
                                           base_blk, out + (size_t)N_TOK * CDIM,
                                           tokmap);
  gather2<<<dim3(NBLK), 256, 0, stream>>>(x, tprob, be, base_blk,
                                          xgT, tokmap, tpg);
  transpose_w<<<dim3(CDIM / 64, HDIM / 64, NEXP), 256, 0, stream>>>(
      W1, w1tT, CDIM, HDIM);
  ffn_p<12, 48, true><<<dim3(72, 24), 256, 0, stream>>>(
      xgT, w1tT, b1, off, nullptr, nullptr, hbufT, nullptr);
  transpose_w<<<dim3(HDIM / 64, CDIM / 64, NEXP), 256, 0, stream>>>(
      W2, w2tT, HDIM, CDIM);
  ffn_p<48, 12, false><<<dim3(72, 6), 256, 0, stream>>>(
      hbufT, w2tT, b2, off, tokmap, tpg, nullptr, out);
}